// Round 1
// baseline (540.438 us; speedup 1.0000x reference)
//
#include <hip/hip_runtime.h>

typedef __bf16 bf16;
typedef __bf16 bf16x8 __attribute__((ext_vector_type(8)));
typedef float f32x4 __attribute__((ext_vector_type(4)));

constexpr int BATCH = 32;
constexpr int SEQ   = 1024;
constexpr int CDIM  = 768;
constexpr int ROWS  = BATCH * SEQ;   // 32768
constexpr int QKVC  = 3 * CDIM;      // 2304

// ---- workspace layout (bytes). total need ~273.3 MB ----
constexpr size_t oWqT = 0;                                   // bf16 WqkvT [2304][768]
constexpr size_t oWpT = oWqT + (size_t)QKVC * CDIM * 2;      // bf16 WprojT [768][768]
constexpr size_t oQKV = oWpT + (size_t)CDIM * CDIM * 2;      // bf16 qkv [32768][2304]
constexpr size_t oS   = oQKV + (size_t)ROWS * QKVC * 2;      // bf16 S [32][1024][1024]
constexpr size_t oVT  = oS   + (size_t)BATCH * SEQ * SEQ * 2;// bf16 VT [32][768][1024]
constexpr size_t oInv = oVT  + (size_t)BATCH * CDIM * SEQ * 2;// f32 invsum [32768]
constexpr size_t oAO  = oQKV; // attn_out aliases qkv (qkv dead after vtrans+QK^T)

// ---------- weight transpose+convert: T[n*768+k] = (bf16) W[k*N + n] ----------
__global__ void wt_kernel(const float* __restrict__ W, bf16* __restrict__ T, int N) {
  int idx = blockIdx.x * blockDim.x + threadIdx.x;
  int total = N * 768;
  if (idx >= total) return;
  int n = idx / 768;
  int k = idx - n * 768;
  T[idx] = (bf16)W[(size_t)k * N + n];
}

// ---------- V transpose: VT[b][c][m] = qkv[b*1024+m][1536+c] ----------
__global__ __launch_bounds__(256) void vtrans_kernel(const bf16* __restrict__ qkv,
                                                     bf16* __restrict__ vt) {
  __shared__ bf16 t[64][68]; // [c][m], pad 68 -> row 136B (8B aligned, conflict-light)
  int b = blockIdx.z, m0 = blockIdx.x * 64, c0 = blockIdx.y * 64;
  int tid = threadIdx.x;
  #pragma unroll
  for (int it = 0; it < 2; ++it) {
    int m = it * 32 + (tid >> 3);
    int c = (tid & 7) * 8;
    bf16x8 v = *(const bf16x8*)(qkv + ((size_t)b * SEQ + m0 + m) * QKVC + 2 * CDIM + c0 + c);
    #pragma unroll
    for (int i = 0; i < 8; ++i) t[c + i][m] = v[i];
  }
  __syncthreads();
  #pragma unroll
  for (int it = 0; it < 2; ++it) {
    int c = it * 32 + (tid >> 3);
    int m = (tid & 7) * 8;
    bf16x8 o;
    #pragma unroll
    for (int i = 0; i < 8; ++i) o[i] = t[c][m + i];
    *(bf16x8*)(vt + ((size_t)b * CDIM + c0 + c) * SEQ + m0 + m) = o;
  }
}

// ---------- rowsum: inv[row] = 1 / sum_m exp(S[row][m]) ----------
__global__ __launch_bounds__(256) void rowsum_kernel(const bf16* __restrict__ S,
                                                     float* __restrict__ inv) {
  int row = blockIdx.x * 4 + (threadIdx.x >> 6);
  int lane = threadIdx.x & 63;
  const bf16* p = S + (size_t)row * SEQ;
  float s = 0.f;
  #pragma unroll
  for (int h = 0; h < 2; ++h) {
    bf16x8 v = *(const bf16x8*)(p + h * 512 + lane * 8);
    #pragma unroll
    for (int i = 0; i < 8; ++i) s += __expf((float)v[i]);
  }
  #pragma unroll
  for (int m = 1; m < 64; m <<= 1) s += __shfl_xor(s, m);
  if (lane == 0) inv[row] = 1.0f / s;
}

// ---------- NT GEMM: C[m][n] = scale*rowScale[m] * sum_k A[m][k]*BT[n][k] + bias[n] ----
// AMODE: 0 = A bf16; 1 = A fp32 (convert in staging); 2 = A bf16 with exp() transform.
// Tile 128x128, BK=64, 4 waves (2x2 of 64x64), 16x16x32 bf16 MFMA.
// LDS XOR swizzle: byte ^= (row&7)<<4 (conflict-free ds_read_b128, G4/T2).
template<int AMODE, bool OUT_BF16, bool HAS_BIAS, bool ROW_SCALE>
__global__ __launch_bounds__(256) void gemm_nt(
    const void* __restrict__ Ap, const bf16* __restrict__ Bp, void* __restrict__ Cp,
    int K, int lda, int ldb, int ldc,
    long sA, long sB, long sC,
    float scale, const float* __restrict__ rowScale, long sRS,
    const float* __restrict__ bias)
{
  __shared__ __align__(16) bf16 As[128 * 64];
  __shared__ __align__(16) bf16 Bs[128 * 64];
  const int tid  = threadIdx.x;
  const int z    = blockIdx.z;
  const int m0   = blockIdx.x * 128;
  const int n0   = blockIdx.y * 128;
  const int lane = tid & 63;
  const int wave = tid >> 6;
  const int wm   = (wave & 1) * 64;
  const int wn   = (wave >> 1) * 64;

  f32x4 acc[4][4] = {};

  const int srow = tid >> 3; // 0..31
  const int scg  = tid & 7;  // 16B chunk 0..7

  for (int kt = 0; kt < K; kt += 64) {
    #pragma unroll
    for (int it = 0; it < 4; ++it) {
      int r  = it * 32 + srow;
      int kc = kt + scg * 8;
      bf16x8 v;
      if (AMODE == 1) {
        const float* a = (const float*)Ap + (size_t)z * sA + (size_t)(m0 + r) * lda + kc;
        float4 f0 = *(const float4*)(a);
        float4 f1 = *(const float4*)(a + 4);
        v[0]=(bf16)f0.x; v[1]=(bf16)f0.y; v[2]=(bf16)f0.z; v[3]=(bf16)f0.w;
        v[4]=(bf16)f1.x; v[5]=(bf16)f1.y; v[6]=(bf16)f1.z; v[7]=(bf16)f1.w;
      } else {
        const bf16* a = (const bf16*)Ap + (size_t)z * sA + (size_t)(m0 + r) * lda + kc;
        v = *(const bf16x8*)a;
        if (AMODE == 2) {
          #pragma unroll
          for (int i = 0; i < 8; ++i) v[i] = (bf16)__expf((float)v[i]);
        }
      }
      *(bf16x8*)((char*)As + r * 128 + ((scg * 16) ^ ((r & 7) << 4))) = v;

      const bf16* bp = Bp + (size_t)z * sB + (size_t)(n0 + r) * ldb + kc;
      bf16x8 w = *(const bf16x8*)bp;
      *(bf16x8*)((char*)Bs + r * 128 + ((scg * 16) ^ ((r & 7) << 4))) = w;
    }
    __syncthreads();
    #pragma unroll
    for (int ks = 0; ks < 2; ++ks) {
      bf16x8 af[4], bfr[4];
      #pragma unroll
      for (int i = 0; i < 4; ++i) {
        int r  = wm + i * 16 + (lane & 15);
        int kb = ks * 64 + ((lane >> 4) * 16);
        af[i]  = *(const bf16x8*)((const char*)As + r * 128 + (kb ^ ((r & 7) << 4)));
        int n  = wn + i * 16 + (lane & 15);
        bfr[i] = *(const bf16x8*)((const char*)Bs + n * 128 + (kb ^ ((n & 7) << 4)));
      }
      #pragma unroll
      for (int i = 0; i < 4; ++i)
        #pragma unroll
        for (int j = 0; j < 4; ++j)
          acc[i][j] = __builtin_amdgcn_mfma_f32_16x16x32_bf16(af[i], bfr[j], acc[i][j], 0, 0, 0);
    }
    __syncthreads();
  }
  // epilogue: C/D layout col=lane&15, row=(lane>>4)*4+reg (m89-verified)
  #pragma unroll
  for (int i = 0; i < 4; ++i) {
    #pragma unroll
    for (int j = 0; j < 4; ++j) {
      #pragma unroll
      for (int r = 0; r < 4; ++r) {
        int gm = m0 + wm + i * 16 + ((lane >> 4) * 4 + r);
        int gn = n0 + wn + j * 16 + (lane & 15);
        float v = acc[i][j][r] * scale;
        if (ROW_SCALE) v *= rowScale[(size_t)z * sRS + gm];
        if (HAS_BIAS)  v += bias[gn];
        if (OUT_BF16) ((bf16*)Cp)[(size_t)z * sC + (size_t)gm * ldc + gn] = (bf16)v;
        else          ((float*)Cp)[(size_t)z * sC + (size_t)gm * ldc + gn] = v;
      }
    }
  }
}

extern "C" void kernel_launch(void* const* d_in, const int* in_sizes, int n_in,
                              void* d_out, int out_size, void* d_ws, size_t ws_size,
                              hipStream_t stream) {
  const float* x     = (const float*)d_in[0];
  const float* Wqkv  = (const float*)d_in[1];
  const float* bqkv  = (const float*)d_in[2];
  const float* Wproj = (const float*)d_in[3];
  const float* bproj = (const float*)d_in[4];
  float* out = (float*)d_out;
  char*  ws  = (char*)d_ws;

  bf16*  WqT = (bf16*)(ws + oWqT);
  bf16*  WpT = (bf16*)(ws + oWpT);
  bf16*  qkv = (bf16*)(ws + oQKV);
  bf16*  S   = (bf16*)(ws + oS);
  bf16*  VT  = (bf16*)(ws + oVT);
  float* inv = (float*)(ws + oInv);
  bf16*  AO  = (bf16*)(ws + oAO);

  const float qk_scale = 1.0f / sqrtf((float)CDIM);

  // 1. weight transpose+convert
  wt_kernel<<<(QKVC * CDIM + 255) / 256, 256, 0, stream>>>(Wqkv, WqT, QKVC);
  wt_kernel<<<(CDIM * CDIM + 255) / 256, 256, 0, stream>>>(Wproj, WpT, CDIM);

  // 2. qkv = bf16(x) @ WqkvT^T + b_qkv   [32768 x 2304]
  gemm_nt<1, true, true, false><<<dim3(ROWS / 128, QKVC / 128, 1), 256, 0, stream>>>(
      x, WqT, qkv, CDIM, CDIM, CDIM, QKVC, 0, 0, 0, 1.0f, nullptr, 0, bqkv);

  // 3. VT[b][c][m] = v
  vtrans_kernel<<<dim3(SEQ / 64, CDIM / 64, BATCH), 256, 0, stream>>>(qkv, VT);

  // 4. S = (q @ k^T) * scale   [32 x 1024 x 1024], bf16
  gemm_nt<0, true, false, false><<<dim3(SEQ / 128, SEQ / 128, BATCH), 256, 0, stream>>>(
      qkv, qkv + CDIM, S, CDIM, QKVC, QKVC, SEQ,
      (long)SEQ * QKVC, (long)SEQ * QKVC, (long)SEQ * SEQ, qk_scale, nullptr, 0, nullptr);

  // 5. invsum = 1/sum exp(S)
  rowsum_kernel<<<ROWS / 4, 256, 0, stream>>>(S, inv);

  // 6. attn_out = (exp(S) @ VT^T) * invsum[row]   [32 x 1024 x 768], bf16
  gemm_nt<2, true, false, true><<<dim3(SEQ / 128, CDIM / 128, BATCH), 256, 0, stream>>>(
      S, VT, AO, SEQ, SEQ, SEQ, CDIM,
      (long)SEQ * SEQ, (long)CDIM * SEQ, (long)SEQ * CDIM, 1.0f, inv, SEQ, nullptr);

  // 7. out = attn_out @ WprojT^T + b_proj   [32768 x 768], fp32
  gemm_nt<0, false, true, false><<<dim3(ROWS / 128, CDIM / 128, 1), 256, 0, stream>>>(
      AO, WpT, out, CDIM, CDIM, CDIM, CDIM, 0, 0, 0, 1.0f, nullptr, 0, bproj);
}

// Round 2
// 506.102 us; speedup vs baseline: 1.0678x; 1.0678x over previous
//
#include <hip/hip_runtime.h>

typedef __bf16 bf16;
typedef __bf16 bf16x8 __attribute__((ext_vector_type(8)));
typedef float f32x4 __attribute__((ext_vector_type(4)));

constexpr int BATCH = 32;
constexpr int SEQ   = 1024;
constexpr int CDIM  = 768;
constexpr int ROWS  = BATCH * SEQ;   // 32768
constexpr int QKVC  = 3 * CDIM;      // 2304

// ---- workspace layout (bytes), ~273.3 MB total ----
constexpr size_t oWqT = 0;                                    // bf16 WqkvT [2304][768]
constexpr size_t oWpT = oWqT + (size_t)QKVC * CDIM * 2;       // bf16 WprojT [768][768]
constexpr size_t oQKV = oWpT + (size_t)CDIM * CDIM * 2;       // bf16 qkv [32768][2304]
constexpr size_t oS   = oQKV + (size_t)ROWS * QKVC * 2;       // bf16 S [32][1024][1024]
constexpr size_t oVT  = oS   + (size_t)BATCH * SEQ * SEQ * 2; // bf16 VT [32][768][1024]
constexpr size_t oInv = oVT  + (size_t)BATCH * CDIM * SEQ * 2;// f32 invsum [32768]
constexpr size_t oAO  = oQKV; // attn_out aliases qkv (dead after vtrans + QK^T)
constexpr size_t oXB  = oS;   // bf16(x) aliases S (dead before QK^T writes S)

__device__ __forceinline__ void gld_lds16(const void* g, void* l) {
  __builtin_amdgcn_global_load_lds(
      (const __attribute__((address_space(1))) unsigned int*)g,
      (__attribute__((address_space(3))) unsigned int*)l,
      16, 0, 0);
}

// ---------- x fp32 -> bf16 ----------
__global__ __launch_bounds__(256) void f2b_kernel(const float* __restrict__ x,
                                                  bf16* __restrict__ y) {
  int i = blockIdx.x * blockDim.x + threadIdx.x;
  const float* p = x + (size_t)i * 8;
  float4 a = *(const float4*)p;
  float4 b = *(const float4*)(p + 4);
  bf16x8 o;
  o[0]=(bf16)a.x; o[1]=(bf16)a.y; o[2]=(bf16)a.z; o[3]=(bf16)a.w;
  o[4]=(bf16)b.x; o[5]=(bf16)b.y; o[6]=(bf16)b.z; o[7]=(bf16)b.w;
  *(bf16x8*)(y + (size_t)i * 8) = o;
}

// ---------- weight transpose+convert (tiled): T[n][k] = bf16(W[k][n]) ----------
__global__ __launch_bounds__(256) void wt_kernel(const float* __restrict__ W,
                                                 bf16* __restrict__ T, int N) {
  __shared__ float t[32][33];
  int k0 = blockIdx.x * 32, n0 = blockIdx.y * 32;
  int tx = threadIdx.x & 31, ty = threadIdx.x >> 5; // 32 x 8
  #pragma unroll
  for (int i = 0; i < 4; ++i)
    t[ty + i * 8][tx] = W[(size_t)(k0 + ty + i * 8) * N + n0 + tx];
  __syncthreads();
  #pragma unroll
  for (int i = 0; i < 4; ++i)
    T[(size_t)(n0 + ty + i * 8) * 768 + k0 + tx] = (bf16)t[tx][ty + i * 8];
}

// ---------- V transpose: VT[b][c][m] = qkv[b*1024+m][1536+c] ----------
__global__ __launch_bounds__(256) void vtrans_kernel(const bf16* __restrict__ qkv,
                                                     bf16* __restrict__ vt) {
  __shared__ bf16 t[64][68];
  int b = blockIdx.z, m0 = blockIdx.x * 64, c0 = blockIdx.y * 64;
  int tid = threadIdx.x;
  #pragma unroll
  for (int it = 0; it < 2; ++it) {
    int m = it * 32 + (tid >> 3);
    int c = (tid & 7) * 8;
    bf16x8 v = *(const bf16x8*)(qkv + ((size_t)b * SEQ + m0 + m) * QKVC + 2 * CDIM + c0 + c);
    #pragma unroll
    for (int i = 0; i < 8; ++i) t[c + i][m] = v[i];
  }
  __syncthreads();
  #pragma unroll
  for (int it = 0; it < 2; ++it) {
    int c = it * 32 + (tid >> 3);
    int m = (tid & 7) * 8;
    bf16x8 o;
    #pragma unroll
    for (int i = 0; i < 8; ++i) o[i] = t[c][m + i];
    *(bf16x8*)(vt + ((size_t)b * CDIM + c0 + c) * SEQ + m0 + m) = o;
  }
}

// ---------- rowsum+exp: S <- bf16(exp(S)) in place; inv[row] = 1/sum(exp) ----------
__global__ __launch_bounds__(256) void rowsum_exp_kernel(bf16* __restrict__ S,
                                                         float* __restrict__ inv) {
  int row = blockIdx.x * 4 + (threadIdx.x >> 6);
  int lane = threadIdx.x & 63;
  bf16* p = S + (size_t)row * SEQ;
  float s = 0.f;
  #pragma unroll
  for (int h = 0; h < 2; ++h) {
    bf16x8 v = *(const bf16x8*)(p + h * 512 + lane * 8);
    bf16x8 o;
    #pragma unroll
    for (int i = 0; i < 8; ++i) {
      float e = __expf((float)v[i]);
      s += e;
      o[i] = (bf16)e;
    }
    *(bf16x8*)(p + h * 512 + lane * 8) = o;
  }
  #pragma unroll
  for (int m = 1; m < 64; m <<= 1) s += __shfl_xor(s, m);
  if (lane == 0) inv[row] = 1.0f / s;
}

// ---------- NT GEMM, m97 pattern: 128x128 tile, BK=64, 4 waves, global_load_lds w16 ----
// C[z][m][n] = scale*rowScale[z][m] * sum_k A[z][m][k]*B[z][n][k] + bias[n]
// 1-D grid, XCD-chunked bijective swizzle over (z, mt, nt), nt fastest.
template<bool OUT_BF16, bool HAS_BIAS, bool ROW_SCALE>
__global__ __launch_bounds__(256) void gemm_nt(
    const bf16* __restrict__ Ap, const bf16* __restrict__ Bp, void* __restrict__ Cp,
    int K, int lda, int ldb, int ldc, int ntm, int ntn,
    long sA, long sB, long sC,
    float scale, const float* __restrict__ rowScale, long sRS,
    const float* __restrict__ bias)
{
  __shared__ __align__(16) bf16 As[128 * 64];
  __shared__ __align__(16) bf16 Bs[128 * 64];
  const int tid  = threadIdx.x;
  const int lane = tid & 63;
  const int wv   = tid >> 6;

  // XCD swizzle: grid size is always a multiple of 8 here -> bijective
  const int total = (int)gridDim.x;
  const int chunk = total >> 3;
  const int bid   = (int)blockIdx.x;
  int sbid = (bid & 7) * chunk + (bid >> 3);
  const int pb = ntm * ntn;
  const int z  = sbid / pb;  sbid -= z * pb;
  const int mt = sbid / ntn;
  const int nt = sbid - mt * ntn;
  const int m0 = mt * 128, n0 = nt * 128;

  const bf16* A = Ap + (size_t)z * sA;
  const bf16* B = Bp + (size_t)z * sB;

  const int wm = (wv & 1) * 64;
  const int wn = (wv >> 1) * 64;
  f32x4 acc[4][4] = {};

  for (int kt = 0; kt < K; kt += 64) {
    #pragma unroll
    for (int it = 0; it < 4; ++it) {
      int chunkid = it * 256 + tid;     // 16B chunk id within 128x64 tile
      int r  = chunkid >> 3;            // row 0..127
      int c8 = chunkid & 7;             // 8-elem group 0..7
      gld_lds16(A + (size_t)(m0 + r) * lda + kt + c8 * 8, As + (it * 4 + wv) * 512);
      gld_lds16(B + (size_t)(n0 + r) * ldb + kt + c8 * 8, Bs + (it * 4 + wv) * 512);
    }
    __syncthreads();
    #pragma unroll
    for (int ks = 0; ks < 2; ++ks) {
      bf16x8 af[4], bfr[4];
      #pragma unroll
      for (int i = 0; i < 4; ++i) {
        int rm = wm + i * 16 + (lane & 15);
        int kb = ks * 64 + ((lane >> 4) * 16);   // byte offset in 128B row
        af[i]  = *(const bf16x8*)((const char*)As + rm * 128 + kb);
        int rn = wn + i * 16 + (lane & 15);
        bfr[i] = *(const bf16x8*)((const char*)Bs + rn * 128 + kb);
      }
      #pragma unroll
      for (int i = 0; i < 4; ++i)
        #pragma unroll
        for (int j = 0; j < 4; ++j)
          acc[i][j] = __builtin_amdgcn_mfma_f32_16x16x32_bf16(af[i], bfr[j], acc[i][j], 0, 0, 0);
    }
    __syncthreads();
  }

  // epilogue: C/D layout col=lane&15, row=(lane>>4)*4+reg (m89-verified)
  #pragma unroll
  for (int i = 0; i < 4; ++i) {
    #pragma unroll
    for (int j = 0; j < 4; ++j) {
      #pragma unroll
      for (int r = 0; r < 4; ++r) {
        int gm = m0 + wm + i * 16 + ((lane >> 4) * 4 + r);
        int gn = n0 + wn + j * 16 + (lane & 15);
        float v = acc[i][j][r] * scale;
        if (ROW_SCALE) v *= rowScale[(size_t)z * sRS + gm];
        if (HAS_BIAS)  v += bias[gn];
        if (OUT_BF16) ((bf16*)Cp)[(size_t)z * sC + (size_t)gm * ldc + gn] = (bf16)v;
        else          ((float*)Cp)[(size_t)z * sC + (size_t)gm * ldc + gn] = v;
      }
    }
  }
}

extern "C" void kernel_launch(void* const* d_in, const int* in_sizes, int n_in,
                              void* d_out, int out_size, void* d_ws, size_t ws_size,
                              hipStream_t stream) {
  const float* x     = (const float*)d_in[0];
  const float* Wqkv  = (const float*)d_in[1];
  const float* bqkv  = (const float*)d_in[2];
  const float* Wproj = (const float*)d_in[3];
  const float* bproj = (const float*)d_in[4];
  float* out = (float*)d_out;
  char*  ws  = (char*)d_ws;

  bf16*  WqT = (bf16*)(ws + oWqT);
  bf16*  WpT = (bf16*)(ws + oWpT);
  bf16*  qkv = (bf16*)(ws + oQKV);
  bf16*  S   = (bf16*)(ws + oS);
  bf16*  VT  = (bf16*)(ws + oVT);
  float* inv = (float*)(ws + oInv);
  bf16*  AO  = (bf16*)(ws + oAO);
  bf16*  xb  = (bf16*)(ws + oXB);

  const float qk_scale = 1.0f / sqrtf((float)CDIM);

  // 1. conversions / transposes
  f2b_kernel<<<ROWS * CDIM / 8 / 256, 256, 0, stream>>>(x, xb);
  wt_kernel<<<dim3(768 / 32, QKVC / 32), 256, 0, stream>>>(Wqkv, WqT, QKVC);
  wt_kernel<<<dim3(768 / 32, CDIM / 32), 256, 0, stream>>>(Wproj, WpT, CDIM);

  // 2. qkv = xb @ WqT^T + b_qkv   [32768 x 2304]
  gemm_nt<true, true, false><<<(ROWS / 128) * (QKVC / 128), 256, 0, stream>>>(
      xb, WqT, qkv, CDIM, CDIM, CDIM, QKVC, ROWS / 128, QKVC / 128,
      0, 0, 0, 1.0f, nullptr, 0, bqkv);

  // 3. VT[b][c][m] = v
  vtrans_kernel<<<dim3(SEQ / 64, CDIM / 64, BATCH), 256, 0, stream>>>(qkv, VT);

  // 4. S = (q @ k^T) * scale   [32 x 1024 x 1024]   (overwrites xb — xb is dead)
  gemm_nt<true, false, false><<<BATCH * (SEQ / 128) * (SEQ / 128), 256, 0, stream>>>(
      qkv, qkv + CDIM, S, CDIM, QKVC, QKVC, SEQ, SEQ / 128, SEQ / 128,
      (long)SEQ * QKVC, (long)SEQ * QKVC, (long)SEQ * SEQ, qk_scale, nullptr, 0, nullptr);

  // 5. S <- exp(S); inv = 1/rowsum
  rowsum_exp_kernel<<<ROWS / 4, 256, 0, stream>>>(S, inv);

  // 6. attn_out = (expS @ VT^T) * inv[row]   [32 x 1024 x 768]
  gemm_nt<true, false, true><<<BATCH * (SEQ / 128) * (CDIM / 128), 256, 0, stream>>>(
      S, VT, AO, SEQ, SEQ, SEQ, CDIM, SEQ / 128, CDIM / 128,
      (long)SEQ * SEQ, (long)CDIM * SEQ, (long)SEQ * CDIM, 1.0f, inv, SEQ, nullptr);

  // 7. out = attn_out @ WpT^T + b_proj   [32768 x 768], fp32
  gemm_nt<false, true, false><<<(ROWS / 128) * (CDIM / 128), 256, 0, stream>>>(
      AO, WpT, out, CDIM, CDIM, CDIM, CDIM, ROWS / 128, CDIM / 128,
      0, 0, 0, 1.0f, nullptr, 0, bproj);
}

// Round 4
// 419.464 us; speedup vs baseline: 1.2884x; 1.2065x over previous
//
#include <hip/hip_runtime.h>

typedef __bf16 bf16;
typedef __bf16 bf16x8 __attribute__((ext_vector_type(8)));
typedef float f32x4 __attribute__((ext_vector_type(4)));

constexpr int BATCH = 32;
constexpr int SEQ   = 1024;
constexpr int CDIM  = 768;
constexpr int ROWS  = BATCH * SEQ;   // 32768
constexpr int QKVC  = 3 * CDIM;      // 2304

// ---- workspace layout (bytes), ~273.3 MB total ----
constexpr size_t oWqT = 0;                                    // bf16 WqkvT [2304][768]
constexpr size_t oWpT = oWqT + (size_t)QKVC * CDIM * 2;       // bf16 WprojT [768][768]
constexpr size_t oQKV = oWpT + (size_t)CDIM * CDIM * 2;       // bf16 qkv [32768][2304]
constexpr size_t oS   = oQKV + (size_t)ROWS * QKVC * 2;       // bf16 S [32][1024][1024]
constexpr size_t oVT  = oS   + (size_t)BATCH * SEQ * SEQ * 2; // bf16 VT [32][768][1024]
constexpr size_t oInv = oVT  + (size_t)BATCH * CDIM * SEQ * 2;// f32 invsum [32768]
constexpr size_t oAO  = oQKV; // attn_out aliases qkv (dead after vtrans + QK^T)
constexpr size_t oXB  = oS;   // bf16(x) aliases S (dead before QK^T writes S)

__device__ __forceinline__ void gld_lds16(const void* g, void* l) {
  __builtin_amdgcn_global_load_lds(
      (const __attribute__((address_space(1))) unsigned int*)g,
      (__attribute__((address_space(3))) unsigned int*)l,
      16, 0, 0);
}

// ---------- x fp32 -> bf16 ----------
__global__ __launch_bounds__(256) void f2b_kernel(const float* __restrict__ x,
                                                  bf16* __restrict__ y) {
  int i = blockIdx.x * blockDim.x + threadIdx.x;
  const float* p = x + (size_t)i * 8;
  float4 a = *(const float4*)p;
  float4 b = *(const float4*)(p + 4);
  bf16x8 o;
  o[0]=(bf16)a.x; o[1]=(bf16)a.y; o[2]=(bf16)a.z; o[3]=(bf16)a.w;
  o[4]=(bf16)b.x; o[5]=(bf16)b.y; o[6]=(bf16)b.z; o[7]=(bf16)b.w;
  *(bf16x8*)(y + (size_t)i * 8) = o;
}

// ---------- weight transpose+convert (tiled): T[n][k] = bf16(W[k][n]) ----------
__global__ __launch_bounds__(256) void wt_kernel(const float* __restrict__ W,
                                                 bf16* __restrict__ T, int N) {
  __shared__ float t[32][33];
  int k0 = blockIdx.x * 32, n0 = blockIdx.y * 32;
  int tx = threadIdx.x & 31, ty = threadIdx.x >> 5; // 32 x 8
  #pragma unroll
  for (int i = 0; i < 4; ++i)
    t[ty + i * 8][tx] = W[(size_t)(k0 + ty + i * 8) * N + n0 + tx];
  __syncthreads();
  #pragma unroll
  for (int i = 0; i < 4; ++i)
    T[(size_t)(n0 + ty + i * 8) * 768 + k0 + tx] = (bf16)t[tx][ty + i * 8];
}

// ---------- V transpose: VT[b][c][m] = qkv[b*1024+m][1536+c] ----------
__global__ __launch_bounds__(256) void vtrans_kernel(const bf16* __restrict__ qkv,
                                                     bf16* __restrict__ vt) {
  __shared__ bf16 t[64][68];
  int b = blockIdx.z, m0 = blockIdx.x * 64, c0 = blockIdx.y * 64;
  int tid = threadIdx.x;
  #pragma unroll
  for (int it = 0; it < 2; ++it) {
    int m = it * 32 + (tid >> 3);
    int c = (tid & 7) * 8;
    bf16x8 v = *(const bf16x8*)(qkv + ((size_t)b * SEQ + m0 + m) * QKVC + 2 * CDIM + c0 + c);
    #pragma unroll
    for (int i = 0; i < 8; ++i) t[c + i][m] = v[i];
  }
  __syncthreads();
  #pragma unroll
  for (int it = 0; it < 2; ++it) {
    int c = it * 32 + (tid >> 3);
    int m = (tid & 7) * 8;
    bf16x8 o;
    #pragma unroll
    for (int i = 0; i < 8; ++i) o[i] = t[c][m + i];
    *(bf16x8*)(vt + ((size_t)b * CDIM + c0 + c) * SEQ + m0 + m) = o;
  }
}

// ---------- rowsum+exp: S <- bf16(exp(S)) in place; inv[row] = 1/sum(exp) ----------
__global__ __launch_bounds__(256) void rowsum_exp_kernel(bf16* __restrict__ S,
                                                         float* __restrict__ inv) {
  int row = blockIdx.x * 4 + (threadIdx.x >> 6);
  int lane = threadIdx.x & 63;
  bf16* p = S + (size_t)row * SEQ;
  float s = 0.f;
  #pragma unroll
  for (int h = 0; h < 2; ++h) {
    bf16x8 v = *(const bf16x8*)(p + h * 512 + lane * 8);
    bf16x8 o;
    #pragma unroll
    for (int i = 0; i < 8; ++i) {
      float e = __expf((float)v[i]);
      s += e;
      o[i] = (bf16)e;
    }
    *(bf16x8*)(p + h * 512 + lane * 8) = o;
  }
  #pragma unroll
  for (int m = 1; m < 64; m <<= 1) s += __shfl_xor(s, m);
  if (lane == 0) inv[row] = 1.0f / s;
}

// ================= 256x256 8-wave phased NT GEMM =================
// C[z][m][n] = scale*rowScale[z][m]*sum_k A[z][m][k]*B[z][n][k] + bias[n]
// BK=64, LDS 2x(A 256x64 + B 256x64) bf16 = 128 KiB double buffer.
// Per K-tile: 4 phases {ds_read frags; (phases 0-1: issue 4 gld_lds for t+1);
// lgkmcnt(0)+sched_barrier; setprio 16xMFMA}. RACE DISCIPLINE (round-3 fix):
// vmcnt(0) BEFORE the end-of-tile s_barrier — vmcnt is per-wave, so each wave
// drains its OWN stages, then the barrier publishes all waves' stages.
// T2 swizzle: linear LDS dest, inverse-swizzled GLOBAL chunk c8^(r&7),
// swizzled ds_read byte kb^((row&7)<<4)  (rule 21: both-sides-or-neither).

#define LOADA(mh_) do {                                                          \
  _Pragma("unroll")                                                              \
  for (int i_ = 0; i_ < 4; ++i_) {                                               \
    const int row_ = wm * 128 + ((mh_) * 4 + i_) * 16 + lr;                      \
    const char* rb_ = (const char*)Acur + row_ * 128;                            \
    af[i_][0] = *(const bf16x8*)(rb_ + ((0  + kb0) ^ swz));                      \
    af[i_][1] = *(const bf16x8*)(rb_ + ((64 + kb0) ^ swz));                      \
  }                                                                              \
} while (0)

#define STAGE2(sp0_, sp1_) do {                                                  \
  if (t + 1 < nkt) {                                                             \
    gld_lds16(Ast + (size_t)((sp0_) * 64) * lda + ktn, Asn + (sp0_) * 4096 + wv * 512); \
    gld_lds16(Bst + (size_t)((sp0_) * 64) * ldb + ktn, Bsn + (sp0_) * 4096 + wv * 512); \
    gld_lds16(Ast + (size_t)((sp1_) * 64) * lda + ktn, Asn + (sp1_) * 4096 + wv * 512); \
    gld_lds16(Bst + (size_t)((sp1_) * 64) * ldb + ktn, Bsn + (sp1_) * 4096 + wv * 512); \
  }                                                                              \
} while (0)

#define PHASE(mh_, nh_, LA_, STG_) do {                                          \
  if (LA_) LOADA(mh_);                                                           \
  bf16x8 bfr[2][2];                                                              \
  _Pragma("unroll")                                                              \
  for (int j_ = 0; j_ < 2; ++j_) {                                               \
    const int row_ = wn * 64 + ((nh_) * 2 + j_) * 16 + lr;                       \
    const char* rb_ = (const char*)Bcur + row_ * 128;                            \
    bfr[j_][0] = *(const bf16x8*)(rb_ + ((0  + kb0) ^ swz));                     \
    bfr[j_][1] = *(const bf16x8*)(rb_ + ((64 + kb0) ^ swz));                     \
  }                                                                              \
  STG_;                                                                          \
  asm volatile("s_waitcnt lgkmcnt(0)" ::: "memory");                             \
  __builtin_amdgcn_sched_barrier(0);                                             \
  __builtin_amdgcn_s_setprio(1);                                                 \
  _Pragma("unroll")                                                              \
  for (int ks_ = 0; ks_ < 2; ++ks_)                                              \
    _Pragma("unroll")                                                            \
    for (int i_ = 0; i_ < 4; ++i_)                                               \
      _Pragma("unroll")                                                          \
      for (int j_ = 0; j_ < 2; ++j_)                                             \
        acc[(mh_) * 4 + i_][(nh_) * 2 + j_] =                                    \
            __builtin_amdgcn_mfma_f32_16x16x32_bf16(af[i_][ks_], bfr[j_][ks_],   \
                acc[(mh_) * 4 + i_][(nh_) * 2 + j_], 0, 0, 0);                   \
  __builtin_amdgcn_s_setprio(0);                                                 \
} while (0)

template<bool OUT_BF16, bool HAS_BIAS, bool ROW_SCALE>
__global__ __launch_bounds__(512, 2) void gemm256(
    const bf16* __restrict__ Ap, const bf16* __restrict__ Bp, void* __restrict__ Cp,
    int K, int lda, int ldb, int ldc, int ntm, int ntn,
    long sA, long sB, long sC,
    float scale, const float* __restrict__ rowScale, long sRS,
    const float* __restrict__ bias)
{
  __shared__ __align__(16) bf16 As[2][256 * 64];
  __shared__ __align__(16) bf16 Bs[2][256 * 64];
  const int tid  = threadIdx.x;
  const int lane = tid & 63;
  const int wv   = tid >> 6;      // 0..7
  const int wm   = wv >> 2;       // 0..1  (128-row half)
  const int wn   = wv & 3;        // 0..3  (64-col strip)

  // XCD-chunked bijective swizzle (grid always a multiple of 8 here)
  const int total = (int)gridDim.x;
  const int chunk = total >> 3;
  const int bid   = (int)blockIdx.x;
  int sbid = (bid & 7) * chunk + (bid >> 3);
  const int pb = ntm * ntn;
  const int z  = sbid / pb;  sbid -= z * pb;
  const int mt = sbid / ntn;
  const int nt = sbid - mt * ntn;
  const int m0 = mt * 256, n0 = nt * 256;

  const bf16* A = Ap + (size_t)z * sA;
  const bf16* B = Bp + (size_t)z * sB;

  // staging map: row sr (0..63 per segment), chunk sc8; global chunk pre-swizzled
  const int sr  = tid >> 3;
  const int sc8 = tid & 7;
  const int gch = sc8 ^ (sr & 7);
  const bf16* Ast = A + (size_t)(m0 + sr) * lda + gch * 8;
  const bf16* Bst = B + (size_t)(n0 + sr) * ldb + gch * 8;

  const int lr  = lane & 15;
  const int swz = (lane & 7) << 4;
  const int kb0 = (lane >> 4) * 16;

  f32x4 acc[8][4] = {};

  // prologue: stage K-tile 0, drain OWN loads, then barrier (publishes all)
  #pragma unroll
  for (int p = 0; p < 4; ++p) {
    gld_lds16(Ast + (size_t)(p * 64) * lda, &As[0][p * 4096 + wv * 512]);
    gld_lds16(Bst + (size_t)(p * 64) * ldb, &Bs[0][p * 4096 + wv * 512]);
  }
  asm volatile("s_waitcnt vmcnt(0)" ::: "memory");
  __builtin_amdgcn_s_barrier();
  __builtin_amdgcn_sched_barrier(0);

  const int nkt = K >> 6;
  int cur = 0;
  for (int t = 0; t < nkt; ++t, cur ^= 1) {
    const bf16* Acur = As[cur];
    const bf16* Bcur = Bs[cur];
    bf16* Asn = As[cur ^ 1];
    bf16* Bsn = Bs[cur ^ 1];
    const int ktn = (t + 1) << 6;
    bf16x8 af[4][2];
    PHASE(0, 0, 1, STAGE2(0, 1));   // stages get ~3 phases of compute cover
    PHASE(0, 1, 0, STAGE2(2, 3));
    PHASE(1, 1, 1, ;);
    PHASE(1, 0, 0, ;);
    asm volatile("s_waitcnt vmcnt(0)" ::: "memory"); // drain OWN stages FIRST
    __builtin_amdgcn_s_barrier();                    // then publish to all waves
    __builtin_amdgcn_sched_barrier(0);
  }

  // epilogue: C/D layout col=lane&15, row=(lane>>4)*4+reg (m89-verified)
  #pragma unroll
  for (int mf = 0; mf < 8; ++mf) {
    #pragma unroll
    for (int nf = 0; nf < 4; ++nf) {
      #pragma unroll
      for (int r = 0; r < 4; ++r) {
        int gm = m0 + wm * 128 + mf * 16 + ((lane >> 4) * 4 + r);
        int gn = n0 + wn * 64 + nf * 16 + (lane & 15);
        float v = acc[mf][nf][r] * scale;
        if (ROW_SCALE) v *= rowScale[(size_t)z * sRS + gm];
        if (HAS_BIAS)  v += bias[gn];
        if (OUT_BF16) ((bf16*)Cp)[(size_t)z * sC + (size_t)gm * ldc + gn] = (bf16)v;
        else          ((float*)Cp)[(size_t)z * sC + (size_t)gm * ldc + gn] = v;
      }
    }
  }
}

extern "C" void kernel_launch(void* const* d_in, const int* in_sizes, int n_in,
                              void* d_out, int out_size, void* d_ws, size_t ws_size,
                              hipStream_t stream) {
  const float* x     = (const float*)d_in[0];
  const float* Wqkv  = (const float*)d_in[1];
  const float* bqkv  = (const float*)d_in[2];
  const float* Wproj = (const float*)d_in[3];
  const float* bproj = (const float*)d_in[4];
  float* out = (float*)d_out;
  char*  ws  = (char*)d_ws;

  bf16*  WqT = (bf16*)(ws + oWqT);
  bf16*  WpT = (bf16*)(ws + oWpT);
  bf16*  qkv = (bf16*)(ws + oQKV);
  bf16*  S   = (bf16*)(ws + oS);
  bf16*  VT  = (bf16*)(ws + oVT);
  float* inv = (float*)(ws + oInv);
  bf16*  AO  = (bf16*)(ws + oAO);
  bf16*  xb  = (bf16*)(ws + oXB);

  const float qk_scale = 1.0f / sqrtf((float)CDIM);

  // 1. conversions / transposes
  f2b_kernel<<<ROWS * CDIM / 8 / 256, 256, 0, stream>>>(x, xb);
  wt_kernel<<<dim3(768 / 32, QKVC / 32), 256, 0, stream>>>(Wqkv, WqT, QKVC);
  wt_kernel<<<dim3(768 / 32, CDIM / 32), 256, 0, stream>>>(Wproj, WpT, CDIM);

  // 2. qkv = xb @ WqT^T + b_qkv   [32768 x 2304]
  gemm256<true, true, false><<<(ROWS / 256) * (QKVC / 256), 512, 0, stream>>>(
      xb, WqT, qkv, CDIM, CDIM, CDIM, QKVC, ROWS / 256, QKVC / 256,
      0, 0, 0, 1.0f, nullptr, 0, bqkv);

  // 3. VT[b][c][m] = v
  vtrans_kernel<<<dim3(SEQ / 64, CDIM / 64, BATCH), 256, 0, stream>>>(qkv, VT);

  // 4. S = (q @ k^T) * scale   [32 x 1024 x 1024]   (overwrites xb — xb is dead)
  gemm256<true, false, false><<<BATCH * (SEQ / 256) * (SEQ / 256), 512, 0, stream>>>(
      qkv, qkv + CDIM, S, CDIM, QKVC, QKVC, SEQ, SEQ / 256, SEQ / 256,
      (long)SEQ * QKVC, (long)SEQ * QKVC, (long)SEQ * SEQ, qk_scale, nullptr, 0, nullptr);

  // 5. S <- exp(S); inv = 1/rowsum
  rowsum_exp_kernel<<<ROWS / 4, 256, 0, stream>>>(S, inv);

  // 6. attn_out = (expS @ VT^T) * inv[row]   [32 x 1024 x 768]
  gemm256<true, false, true><<<BATCH * (SEQ / 256) * (CDIM / 256), 512, 0, stream>>>(
      S, VT, AO, SEQ, SEQ, SEQ, CDIM, SEQ / 256, CDIM / 256,
      (long)SEQ * SEQ, (long)CDIM * SEQ, (long)SEQ * CDIM, 1.0f, inv, SEQ, nullptr);

  // 7. out = attn_out @ WpT^T + b_proj   [32768 x 768], fp32
  gemm256<false, true, false><<<(ROWS / 256) * (CDIM / 256), 512, 0, stream>>>(
      AO, WpT, out, CDIM, CDIM, CDIM, CDIM, ROWS / 256, CDIM / 256,
      0, 0, 0, 1.0f, nullptr, 0, bproj);
}